// Round 9
// baseline (168.634 us; speedup 1.0000x reference)
//
#include <hip/hip_runtime.h>
#include <cstddef>

// QSelfAttention MI355X round 17: deep staging pipeline at 1-resident.
// Post-mortem r16: per-chunk chain ~2.9us at 1 resident block/CU vs
// ~0.8-1.2 at 2-3 resident (r13/r14/r15 fits) -> co-residency halves the
// visible chain; chain itself ~7000cyc. Also: fillBufferAligned (268MB,
// 41us, several/iter) is INSIDE dur_us -> ~80-120us constant harness
// overhead; flash is the dominant controllable term.
// r10/r13 counted-vmcnt nulls were at 2-3 resident (drain already covered
// by cross-block interleave). r16's 1-resident regime is where the drain
// (~700-1200cyc: L2 latency + 40KB DMA sink) is naked, and the only
// geometry with LDS headroom: TRIPLE-buffer K/V (3x40KB + Ps = 139KB),
// prefetch depth 2, vmcnt(10) steady / vmcnt(0) tail only. 3 barriers.
// prep/k1/k4: byte-identical to r16.

typedef unsigned short ushort_t;
typedef __attribute__((ext_vector_type(8))) short bf16x8;
typedef __attribute__((ext_vector_type(4))) float f32x4;
typedef __attribute__((ext_vector_type(2))) float f32x2;
typedef __attribute__((ext_vector_type(2))) unsigned u32x2;

#define QSCALE 0.18033688011112042f  // 0.125 * log2(e)

__device__ __forceinline__ ushort_t f2bf_t(float f) {
  return (ushort_t)(__float_as_uint(f) >> 16);
}
__device__ __forceinline__ unsigned pk2bf(float lo, float hi) {
  return __builtin_amdgcn_perm(__float_as_uint(hi), __float_as_uint(lo),
                               0x07060302u);
}

__device__ __forceinline__ void gload16(const ushort_t* g, ushort_t* l) {
  __builtin_amdgcn_global_load_lds(
      (const __attribute__((address_space(1))) void*)g,
      (__attribute__((address_space(3))) void*)l, 16, 0, 0);
}

// ---------------------------------------------------------------------------
// 512-thread NT GEMM: D[128][128] = A[128x512] * B[128x512]^T, bf16, fp32 acc.
// 8 waves in 2x4 grid: wave-tile 64x32, acc[4][2]. (k1/k4.)
__device__ __forceinline__ void gemm512(
    const ushort_t* __restrict__ A, int lda,
    const ushort_t* __restrict__ B, int ldb,
    int m0, int n0, ushort_t* As, ushort_t* Bs, f32x4 (*acc)[2])
{
  const int t = threadIdx.x;
  const int lane = t & 63, quad = lane >> 4, l15 = lane & 15;
  const int w = t >> 6, wm = w >> 2, wn4 = w & 3;
  const int rr = (lane >> 3) & 7;
  const int gg = (lane & 7) ^ rr;

  #pragma unroll
  for (int i = 0; i < 4; ++i)
    #pragma unroll
    for (int j = 0; j < 2; ++j) acc[i][j] = (f32x4){0.f, 0.f, 0.f, 0.f};

  for (int k0 = 0; k0 < 512; k0 += 64) {
    __syncthreads();
    #pragma unroll
    for (int i = 0; i < 2; ++i) {
      const int mrow = w * 16 + i * 8;
      gload16(A + (size_t)(m0 + mrow + rr) * lda + k0 + gg * 8, As + mrow * 64);
      gload16(B + (size_t)(n0 + mrow + rr) * ldb + k0 + gg * 8, Bs + mrow * 64);
    }
    __syncthreads();
    #pragma unroll
    for (int kk = 0; kk < 2; ++kk) {
      const int gq = kk * 4 + quad;
      const int sg = (gq ^ (l15 & 7)) * 8;
      bf16x8 af[4], bfr[2];
      #pragma unroll
      for (int i = 0; i < 4; ++i)
        af[i] = *(const bf16x8*)(As + (wm * 64 + i * 16 + l15) * 64 + sg);
      #pragma unroll
      for (int j = 0; j < 2; ++j)
        bfr[j] = *(const bf16x8*)(Bs + (wn4 * 32 + j * 16 + l15) * 64 + sg);
      #pragma unroll
      for (int i = 0; i < 4; ++i)
        #pragma unroll
        for (int j = 0; j < 2; ++j)
          acc[i][j] = __builtin_amdgcn_mfma_f32_16x16x32_bf16(
              af[i], bfr[j], acc[i][j], 0, 0, 0);
    }
  }
  __syncthreads();
}

template <class F>
__device__ __forceinline__ void store_bf16_512(
    ushort_t* lds, ushort_t* __restrict__ out, int ldo, int m0, int n0,
    f32x4 (*acc)[2], F f)
{
  const int t = threadIdx.x;
  const int lane = t & 63, quad = lane >> 4, l15 = lane & 15;
  const int w = t >> 6, wm = w >> 2, wn4 = w & 3;
  #pragma unroll
  for (int i = 0; i < 4; ++i)
    #pragma unroll
    for (int j = 0; j < 2; ++j)
      #pragma unroll
      for (int r = 0; r < 4; ++r) {
        const int rl = wm * 64 + i * 16 + quad * 4 + r;
        const int cl = wn4 * 32 + j * 16 + l15;
        lds[rl * 136 + cl] = f2bf_t(f(i, j, r, acc[i][j][r]));
      }
  __syncthreads();
  #pragma unroll
  for (int i = 0; i < 4; ++i) {
    const int s = i * 512 + t, m = s >> 4, g = s & 15;
    const uint4 v = *(const uint4*)(lds + m * 136 + g * 8);
    *(uint4*)(out + (size_t)(m0 + m) * ldo + n0 + g * 8) = v;
  }
}

// ---------------------------------------------------------------------------
// prep: x[b][c][n] fp32 -> xbfT[b][n][c] bf16 + weight conversions.
__global__ __launch_bounds__(256) void prep_x(
    const float* __restrict__ x,
    const float* __restrict__ Wq, const float* __restrict__ Wk,
    const float* __restrict__ Wv, const float* __restrict__ Wo,
    ushort_t* __restrict__ xbfT, ushort_t* __restrict__ Wqk,
    ushort_t* __restrict__ Wvb, ushort_t* __restrict__ Wob)
{
  __shared__ float T[64 * 66];
  const int t = threadIdx.x;
  if (blockIdx.y == 8) {
    const int id = blockIdx.z * 16 + blockIdx.x;
    #pragma unroll
    for (int p = 0; p < 5; ++p) {
      const int s = p * 256 + t;
      if (s < 1152) {
        const int u = id * 1152 + s;
        const int e = u * 2;
        float f0, f1;
        if (e < 32768)       { f0 = Wq[e];         f1 = Wq[e + 1]; }
        else if (e < 65536)  { f0 = Wk[e - 32768]; f1 = Wk[e - 32767]; }
        else if (e < 327680) { f0 = Wv[e - 65536]; f1 = Wv[e - 65535]; }
        else                 { f0 = Wo[e - 327680]; f1 = Wo[e - 327679]; }
        const unsigned pk = pk2bf(f0, f1);
        if (e < 65536)       *((unsigned*)Wqk + u) = pk;
        else if (e < 327680) *((unsigned*)Wvb + (u - 32768)) = pk;
        else                 *((unsigned*)Wob + (u - 163840)) = pk;
      }
    }
    return;
  }
  const int b = blockIdx.z, c0 = blockIdx.y * 64, n0 = blockIdx.x * 64;
  const float* xb = x + ((size_t)b * 512 + c0) * 1024 + n0;
  const int njf = t & 15, ci0 = t >> 4;
  #pragma unroll
  for (int p = 0; p < 4; ++p) {
    const int ci = p * 16 + ci0;
    const f32x4 v = *(const f32x4*)(xb + (size_t)ci * 1024 + njf * 4);
    float* d = &T[ci * 66 + njf * 4];
    *(f32x2*)(d)     = (f32x2){v[0], v[1]};
    *(f32x2*)(d + 2) = (f32x2){v[2], v[3]};
  }
  __syncthreads();
  const int c4 = (t & 15) * 4, nr0 = t >> 4;
  #pragma unroll
  for (int p = 0; p < 4; ++p) {
    const int nr = p * 16 + nr0;
    const float a0 = T[(c4 + 0) * 66 + nr];
    const float a1 = T[(c4 + 1) * 66 + nr];
    const float a2 = T[(c4 + 2) * 66 + nr];
    const float a3 = T[(c4 + 3) * 66 + nr];
    const u32x2 pkv = {pk2bf(a0, a1), pk2bf(a2, a3)};
    *(u32x2*)&xbfT[((size_t)b * 1024 + n0 + nr) * 512 + c0 + c4] = pkv;
  }
}

// ---------------------------------------------------------------------------
// k1 fused (512 threads): 640 blocks = 8 XCD x 80; wid batch-contiguous.
__global__ __launch_bounds__(512) void k1_fused(
    const ushort_t* __restrict__ xbfT, const ushort_t* __restrict__ Wqk,
    const ushort_t* __restrict__ Wvb,
    const float* __restrict__ bq, const float* __restrict__ bk,
    const float* __restrict__ bv,
    ushort_t* __restrict__ qkt, ushort_t* __restrict__ vt2)
{
  __shared__ __align__(16) ushort_t lds[17408];
  const unsigned lin = blockIdx.x;
  const unsigned wid = (lin & 7) * 80 + (lin >> 3);
  const int b = wid / 40, r = wid % 40;
  const int t = threadIdx.x, lane = t & 63, quad = lane >> 4, l15 = lane & 15;
  const int w = t >> 6, wm = w >> 2, wn4 = w & 3;
  f32x4 acc[4][2];
  if (r < 32) {
    const int m0 = (r >> 3) * 128, n0 = (r & 7) * 128;
    gemm512(Wvb, 512, xbfT + (size_t)b * 524288, 512, m0, n0,
            lds, lds + 8192, acc);
    float br[4][4];
    #pragma unroll
    for (int i = 0; i < 4; ++i)
      #pragma unroll
      for (int r2 = 0; r2 < 4; ++r2)
        br[i][r2] = bv[m0 + wm * 64 + i * 16 + quad * 4 + r2];
    store_bf16_512(lds, vt2 + (size_t)b * 524288, 1024, m0, n0, acc,
        [&](int i, int, int r2, float v) { return v + br[i][r2]; });
  } else {
    const int m0 = (r - 32) * 128;
    gemm512(xbfT + (size_t)b * 524288, 512, Wqk, 512, m0, 0,
            lds, lds + 8192, acc);
    float bc[2], qs[2];
    #pragma unroll
    for (int j = 0; j < 2; ++j) {
      const int col = wn4 * 32 + j * 16 + l15;
      bc[j] = (col < 64) ? bq[col] : bk[col - 64];
      qs[j] = (col < 64) ? QSCALE : 1.0f;
    }
    store_bf16_512(lds, qkt + (size_t)b * 131072, 128, m0, 0, acc,
        [&](int, int j, int, float v) { return (v + bc[j]) * qs[j]; });
  }
}

// ---------------------------------------------------------------------------
// flash (512 threads): per block (b, 128 q-rows m0, 256 c-cols c0);
// 16 chunks x 64 keys. Grid 256 = 1 block/CU.
// Triple-buffered staging, prefetch depth 2, counted vmcnt:
//   prologue: stage Q -> regs (lgkm-drained); STAGE(0,slot0); STAGE(1,slot1)
//   iter t: [STAGE(t+2, slot (t+2)%3)] ; vmcnt(10|5|0) ; bar B ;
//           S from slot t%3 ; exp2 -> Ps ; lgkm(0) ; bar C ;
//           PV from Ps + Vs slot t%3 ; lgkm(0) ; bar A
// WAR: slot s rewritten only by STAGE(t+3) issued after bar A of t.
// LDS: 3 x (Ks 8KB + Vs 32KB) = 120KB | Ps[128][72] 18KB | lsum 1KB = 139KB.
__global__ __launch_bounds__(512) void flash_attn(
    const ushort_t* __restrict__ qkt, const ushort_t* __restrict__ vt2,
    ushort_t* __restrict__ o1)
{
  __shared__ __align__(16) ushort_t buf[70656];  // 3*20480 slots + 9216 Ps
  __shared__ float lsum[128][2];
  ushort_t* Ps = buf + 61440;    // 9216 ush (stride 72); Q-stage uses 8192

  const int t = threadIdx.x;
  const int lane = t & 63, quad = lane >> 4, l15 = lane & 15;
  const int w = t >> 6, wm = w >> 1, wn2 = w & 1;
  const int rr = (lane >> 3) & 7, gg = (lane & 7) ^ rr;

  // bijective XCD swizzle over 256 blocks: XCD k owns batches {2k,2k+1}
  const unsigned lin = blockIdx.x;
  const unsigned wid = (lin & 7) * 32 + (lin >> 3);
  const int b  = wid >> 4;
  const int m0 = ((wid >> 1) & 7) * 128;
  const int c0 = (wid & 1) * 256;

  const ushort_t* qb = qkt + (size_t)b * 131072;   // [n][128]: q 0..63, k 64..127
  const ushort_t* vb = vt2 + (size_t)b * 524288;   // [c][1024]

  // ---- prologue: stage Q (128x64) into Ps region -> registers
  #pragma unroll
  for (int i = 0; i < 2; ++i) {
    const int row = w * 16 + i * 8;
    gload16(qb + (size_t)(m0 + row + rr) * 128 + gg * 8, Ps + row * 64);
  }
  asm volatile("s_waitcnt vmcnt(0)" ::: "memory");
  __builtin_amdgcn_sched_barrier(0);
  __builtin_amdgcn_s_barrier();
  bf16x8 af_q[2][2];
  #pragma unroll
  for (int kk = 0; kk < 2; ++kk) {
    const int sg = ((kk * 4 + quad) ^ (l15 & 7)) * 8;
    #pragma unroll
    for (int i = 0; i < 2; ++i)
      af_q[i][kk] = *(const bf16x8*)(Ps + (wm * 32 + i * 16 + l15) * 64 + sg);
  }
  // own Q-frag ds_reads retired before any Ps overwrite (first write is
  // after barrier B of t=0, which follows this wave's lgkm drain).
  asm volatile("s_waitcnt lgkmcnt(0)" ::: "memory");
  __builtin_amdgcn_sched_barrier(0);

  // stage chunks 0 and 1 into slots 0 and 1 (5 loads/thread each)
  auto stage = [&](int mc, int slot) {
    ushort_t* Kd = buf + slot * 20480;
    ushort_t* Vd = Kd + 4096;
    gload16(qb + (size_t)(mc + w * 8 + rr) * 128 + 64 + gg * 8,
            Kd + (w * 8) * 64);
    #pragma unroll
    for (int i = 0; i < 4; ++i)
      gload16(vb + (size_t)(c0 + w * 32 + i * 8 + rr) * 1024 + mc + gg * 8,
              Vd + (w * 32 + i * 8) * 64);
  };
  stage(0, 0);
  stage(64, 1);

  f32x4 accO[2][8];
  #pragma unroll
  for (int i = 0; i < 2; ++i)
    #pragma unroll
    for (int j = 0; j < 8; ++j) accO[i][j] = (f32x4){0.f, 0.f, 0.f, 0.f};
  float rsum[2][4] = {{0.f, 0.f, 0.f, 0.f}, {0.f, 0.f, 0.f, 0.f}};

  ushort_t* ps_w = Ps + (wm * 32 + quad * 4) * 72 + wn2 * 32 + l15;
  const int sg0 = (quad ^ (l15 & 7)) * 8;
  const int sg1 = ((4 + quad) ^ (l15 & 7)) * 8;

  int slot = 0;
  #pragma unroll 1
  for (int mc = 0; mc < 1024; mc += 64) {
    ushort_t* Ks = buf + slot * 20480;
    ushort_t* Vs = Ks + 4096;

    // 1) prefetch chunk t+2 into slot (t+2)%3; counted wait for chunk t.
    if (mc < 896) {
      const int ns = slot < 1 ? slot + 2 : slot - 1;  // (t+2)%3
      stage(mc + 128, ns);
      asm volatile("s_waitcnt vmcnt(10)" ::: "memory");
    } else if (mc == 896) {
      asm volatile("s_waitcnt vmcnt(5)" ::: "memory");
    } else {
      asm volatile("s_waitcnt vmcnt(0)" ::: "memory");
    }
    __builtin_amdgcn_sched_barrier(0);
    __builtin_amdgcn_s_barrier();  // B: slot t visible to all waves

    // 2) S-phase: rows wm*32+{0,16}, keys wn2*32+{0,16}, K=64 (Q pre-scaled)
    f32x4 accS[2][2];
    #pragma unroll
    for (int i = 0; i < 2; ++i)
      #pragma unroll
      for (int j = 0; j < 2; ++j) accS[i][j] = (f32x4){0.f, 0.f, 0.f, 0.f};
    #pragma unroll
    for (int kk = 0; kk < 2; ++kk) {
      const int sg = kk ? sg1 : sg0;
      bf16x8 bk_[2];
      #pragma unroll
      for (int j = 0; j < 2; ++j)
        bk_[j] = *(const bf16x8*)(Ks + (wn2 * 32 + j * 16 + l15) * 64 + sg);
      #pragma unroll
      for (int i = 0; i < 2; ++i)
        #pragma unroll
        for (int j = 0; j < 2; ++j)
          accS[i][j] = __builtin_amdgcn_mfma_f32_16x16x32_bf16(
              af_q[i][kk], bk_[j], accS[i][j], 0, 0, 0);
    }
    // 3) exp2 -> rsum partials -> Ps (trunc bf16); 16 values/thread
    #pragma unroll
    for (int i = 0; i < 2; ++i)
      #pragma unroll
      for (int j = 0; j < 2; ++j)
        #pragma unroll
        for (int r2 = 0; r2 < 4; ++r2) {
          const float e = __builtin_amdgcn_exp2f(accS[i][j][r2]);
          rsum[i][r2] += e;
          ps_w[(i * 16 + r2) * 72 + j * 16] = f2bf_t(e);
        }
    asm volatile("s_waitcnt lgkmcnt(0)" ::: "memory");
    __builtin_amdgcn_sched_barrier(0);
    __builtin_amdgcn_s_barrier();  // C: Ps visible

    // 4) PV-phase: O[128][256] += Ps[128][64] . Vs[256][64]^T
    #pragma unroll
    for (int kk = 0; kk < 2; ++kk) {
      const int gq = kk * 4 + quad;
      const int sgv = kk ? sg1 : sg0;
      bf16x8 ap[2], bv_[8];
      #pragma unroll
      for (int i = 0; i < 2; ++i)
        ap[i] = *(const bf16x8*)(Ps + (wm * 32 + i * 16 + l15) * 72 + gq * 8);
      #pragma unroll
      for (int j = 0; j < 8; ++j)
        bv_[j] = *(const bf16x8*)(Vs + (wn2 * 128 + j * 16 + l15) * 64 + sgv);
      #pragma unroll
      for (int i = 0; i < 2; ++i)
        #pragma unroll
        for (int j = 0; j < 8; ++j)
          accO[i][j] = __builtin_amdgcn_mfma_f32_16x16x32_bf16(
              ap[i], bv_[j], accO[i][j], 0, 0, 0);
    }
    // 5) PV reads retired -> barrier A: slot t may be overwritten by the
    //    STAGE(t+3) issued next iteration; Ps writable at t+1's exp2.
    asm volatile("s_waitcnt lgkmcnt(0)" ::: "memory");
    __builtin_amdgcn_sched_barrier(0);
    __builtin_amdgcn_s_barrier();  // A

    slot = slot < 2 ? slot + 1 : 0;
  }

  // row sums: reduce over 16 key-lanes; lsum[row][wn2] = 32-key partial
  #pragma unroll
  for (int i = 0; i < 2; ++i)
    #pragma unroll
    for (int r2 = 0; r2 < 4; ++r2) {
      float s = rsum[i][r2];
      #pragma unroll
      for (int d = 1; d < 16; d <<= 1) s += __shfl_xor(s, d, 16);
      if (l15 == 0) lsum[wm * 32 + i * 16 + quad * 4 + r2][wn2] = s;
    }
  __syncthreads();  // last PV reads done; lsum visible

  // epilogue in two 64-row halves through fl_b[64][264] (16896 ush)
  ushort_t* fl_b = buf;
  #pragma unroll
  for (int h = 0; h < 2; ++h) {
    if ((wm >> 1) == h) {
      #pragma unroll
      for (int i = 0; i < 2; ++i)
        #pragma unroll
        for (int r2 = 0; r2 < 4; ++r2) {
          const int row = wm * 32 + i * 16 + quad * 4 + r2;
          const float inv = 1.0f / (lsum[row][0] + lsum[row][1]);
          #pragma unroll
          for (int j = 0; j < 8; ++j)
            fl_b[(row - h * 64) * 264 + wn2 * 128 + j * 16 + l15] =
                f2bf_t(accO[i][j][r2] * inv);
        }
    }
    __syncthreads();
    #pragma unroll
    for (int pp = 0; pp < 4; ++pp) {
      const int s = pp * 512 + t, m = s >> 5, g = s & 31;
      const uint4 v = *(const uint4*)(fl_b + m * 264 + g * 8);
      *(uint4*)(o1 + ((size_t)b * 1024 + m0 + h * 64 + m) * 512 + c0 + g * 8) = v;
    }
    __syncthreads();
  }
}

// ---------------------------------------------------------------------------
// K4 (512 threads): out[b][c][n] = g*(Wo @ o1^T + bo) + x. Exact fp32 path.
__global__ __launch_bounds__(512) void k4_proj(
    const ushort_t* __restrict__ Wob, const ushort_t* __restrict__ o1,
    const float* __restrict__ bo, const float* __restrict__ gamma,
    const float* __restrict__ x, float* __restrict__ out)
{
  __shared__ __align__(16) ushort_t lds[17408];
  const unsigned lin = blockIdx.x;
  const unsigned wid = (lin & 7) * 64 + (lin >> 3);
  const int b = wid >> 5, rem = wid & 31;
  const int m0 = (rem >> 3) * 128, n0 = (rem & 7) * 128;
  f32x4 acc[4][2];
  gemm512(Wob, 512, o1 + (size_t)b * 524288, 512, m0, n0,
          lds, lds + 8192, acc);
  const int t = threadIdx.x, lane = t & 63, quad = lane >> 4, l15 = lane & 15;
  const int w = t >> 6, wm = w >> 2, wn4 = w & 3;
  const float g = gamma[0];
  float br[4][4];
  #pragma unroll
  for (int i = 0; i < 4; ++i)
    #pragma unroll
    for (int r2 = 0; r2 < 4; ++r2)
      br[i][r2] = bo[m0 + wm * 64 + i * 16 + quad * 4 + r2];
  float* fl = (float*)lds;  // 64 rows x 132 f stride (33792 B)
  #pragma unroll
  for (int h = 0; h < 2; ++h) {
    if (wm == h) {
      #pragma unroll
      for (int i = 0; i < 4; ++i)
        #pragma unroll
        for (int j = 0; j < 2; ++j)
          #pragma unroll
          for (int r2 = 0; r2 < 4; ++r2)
            fl[(i * 16 + quad * 4 + r2) * 132 + wn4 * 32 + j * 16 + l15] =
                g * (acc[i][j][r2] + br[i][r2]);
    }
    __syncthreads();
    #pragma unroll
    for (int i2 = 0; i2 < 4; ++i2) {
      const int s = i2 * 512 + t, m = s >> 5, c4 = s & 31;
      f32x4 v = *(const f32x4*)(fl + m * 132 + c4 * 4);
      const size_t gi = ((size_t)b * 512 + m0 + h * 64 + m) * 1024 + n0 + c4 * 4;
      const f32x4 xr = *(const f32x4*)(x + gi);
      v += xr;
      *(f32x4*)(out + gi) = v;
    }
    __syncthreads();
  }
}

// ---------------------------------------------------------------------------
extern "C" void kernel_launch(void* const* d_in, const int* in_sizes, int n_in,
                              void* d_out, int out_size, void* d_ws, size_t ws_size,
                              hipStream_t stream) {
  const float* x     = (const float*)d_in[0];
  const float* Wq    = (const float*)d_in[1];
  const float* bq    = (const float*)d_in[2];
  const float* Wk    = (const float*)d_in[3];
  const float* bk    = (const float*)d_in[4];
  const float* Wv    = (const float*)d_in[5];
  const float* bv    = (const float*)d_in[6];
  const float* Wo    = (const float*)d_in[7];
  const float* bo    = (const float*)d_in[8];
  const float* gamma = (const float*)d_in[9];
  float* out = (float*)d_out;

  char* wsp = (char*)d_ws;
  ushort_t* xbfT   = (ushort_t*)wsp;  wsp += (size_t)16 * 1024 * 512 * 2;  // 16 MB
  ushort_t* Wqk_bf = (ushort_t*)wsp;  wsp += (size_t)128 * 512 * 2;
  ushort_t* Wv_bf  = (ushort_t*)wsp;  wsp += (size_t)512 * 512 * 2;
  ushort_t* Wo_bf  = (ushort_t*)wsp;  wsp += (size_t)512 * 512 * 2;
  ushort_t* qkt    = (ushort_t*)wsp;  wsp += (size_t)16 * 1024 * 128 * 2;  // 4 MB
  ushort_t* vt2    = (ushort_t*)wsp;  wsp += (size_t)16 * 512 * 1024 * 2;  // 16 MB
  ushort_t* o1     = xbfT;  // xbfT dead after k1; reuse for o1

  prep_x    <<<dim3(16, 9, 16), 256, 0, stream>>>(x, Wq, Wk, Wv, Wo,
                                                  xbfT, Wqk_bf, Wv_bf, Wo_bf);
  k1_fused  <<<640, 512, 0, stream>>>(xbfT, Wqk_bf, Wv_bf, bq, bk, bv, qkt, vt2);
  flash_attn<<<256, 512, 0, stream>>>(qkt, vt2, o1);
  k4_proj   <<<512, 512, 0, stream>>>(Wo_bf, o1, bo, gamma, x, out);
}

// Round 11
// 162.694 us; speedup vs baseline: 1.0365x; 1.0365x over previous
//
#include <hip/hip_runtime.h>
#include <cstddef>

// QSelfAttention MI355X round 19: r18 resubmit (infra failure, no counters —
// same signature as r11: died before push/pytest; r11's identical resubmit
// passed). Kernel = r14 restoration (162.4us measured) + T5 setprio pairs
// in flash (priority hint only; no sync/ordering/control-flow effect).
// Session law (r13-r17): flash ~= iters/CU x cost(residency); cost ~2.9us
// @1-resident, ~1.1 @2, ~0.85 @3. r14 (q64xc256, KVBLK64, 512 blocks,
// 2-resident, 32 iters/CU) is the geometry-family optimum.

typedef unsigned short ushort_t;
typedef __attribute__((ext_vector_type(8))) short bf16x8;
typedef __attribute__((ext_vector_type(4))) float f32x4;
typedef __attribute__((ext_vector_type(2))) float f32x2;
typedef __attribute__((ext_vector_type(2))) unsigned u32x2;

#define QSCALE 0.18033688011112042f  // 0.125 * log2(e)

__device__ __forceinline__ ushort_t f2bf_t(float f) {
  return (ushort_t)(__float_as_uint(f) >> 16);
}
__device__ __forceinline__ unsigned pk2bf(float lo, float hi) {
  return __builtin_amdgcn_perm(__float_as_uint(hi), __float_as_uint(lo),
                               0x07060302u);
}

__device__ __forceinline__ void gload16(const ushort_t* g, ushort_t* l) {
  __builtin_amdgcn_global_load_lds(
      (const __attribute__((address_space(1))) void*)g,
      (__attribute__((address_space(3))) void*)l, 16, 0, 0);
}

// ---------------------------------------------------------------------------
// 512-thread NT GEMM: D[128][128] = A[128x512] * B[128x512]^T, bf16, fp32 acc.
// 8 waves in 2x4 grid: wave-tile 64x32, acc[4][2]. (k1/k4.)
__device__ __forceinline__ void gemm512(
    const ushort_t* __restrict__ A, int lda,
    const ushort_t* __restrict__ B, int ldb,
    int m0, int n0, ushort_t* As, ushort_t* Bs, f32x4 (*acc)[2])
{
  const int t = threadIdx.x;
  const int lane = t & 63, quad = lane >> 4, l15 = lane & 15;
  const int w = t >> 6, wm = w >> 2, wn4 = w & 3;
  const int rr = (lane >> 3) & 7;
  const int gg = (lane & 7) ^ rr;

  #pragma unroll
  for (int i = 0; i < 4; ++i)
    #pragma unroll
    for (int j = 0; j < 2; ++j) acc[i][j] = (f32x4){0.f, 0.f, 0.f, 0.f};

  for (int k0 = 0; k0 < 512; k0 += 64) {
    __syncthreads();
    #pragma unroll
    for (int i = 0; i < 2; ++i) {
      const int mrow = w * 16 + i * 8;
      gload16(A + (size_t)(m0 + mrow + rr) * lda + k0 + gg * 8, As + mrow * 64);
      gload16(B + (size_t)(n0 + mrow + rr) * ldb + k0 + gg * 8, Bs + mrow * 64);
    }
    __syncthreads();
    #pragma unroll
    for (int kk = 0; kk < 2; ++kk) {
      const int gq = kk * 4 + quad;
      const int sg = (gq ^ (l15 & 7)) * 8;
      bf16x8 af[4], bfr[2];
      #pragma unroll
      for (int i = 0; i < 4; ++i)
        af[i] = *(const bf16x8*)(As + (wm * 64 + i * 16 + l15) * 64 + sg);
      #pragma unroll
      for (int j = 0; j < 2; ++j)
        bfr[j] = *(const bf16x8*)(Bs + (wn4 * 32 + j * 16 + l15) * 64 + sg);
      #pragma unroll
      for (int i = 0; i < 4; ++i)
        #pragma unroll
        for (int j = 0; j < 2; ++j)
          acc[i][j] = __builtin_amdgcn_mfma_f32_16x16x32_bf16(
              af[i], bfr[j], acc[i][j], 0, 0, 0);
    }
  }
  __syncthreads();
}

template <class F>
__device__ __forceinline__ void store_bf16_512(
    ushort_t* lds, ushort_t* __restrict__ out, int ldo, int m0, int n0,
    f32x4 (*acc)[2], F f)
{
  const int t = threadIdx.x;
  const int lane = t & 63, quad = lane >> 4, l15 = lane & 15;
  const int w = t >> 6, wm = w >> 2, wn4 = w & 3;
  #pragma unroll
  for (int i = 0; i < 4; ++i)
    #pragma unroll
    for (int j = 0; j < 2; ++j)
      #pragma unroll
      for (int r = 0; r < 4; ++r) {
        const int rl = wm * 64 + i * 16 + quad * 4 + r;
        const int cl = wn4 * 32 + j * 16 + l15;
        lds[rl * 136 + cl] = f2bf_t(f(i, j, r, acc[i][j][r]));
      }
  __syncthreads();
  #pragma unroll
  for (int i = 0; i < 4; ++i) {
    const int s = i * 512 + t, m = s >> 4, g = s & 15;
    const uint4 v = *(const uint4*)(lds + m * 136 + g * 8);
    *(uint4*)(out + (size_t)(m0 + m) * ldo + n0 + g * 8) = v;
  }
}

// ---------------------------------------------------------------------------
// prep: x[b][c][n] fp32 -> xbfT[b][n][c] bf16 + weight conversions.
__global__ __launch_bounds__(256) void prep_x(
    const float* __restrict__ x,
    const float* __restrict__ Wq, const float* __restrict__ Wk,
    const float* __restrict__ Wv, const float* __restrict__ Wo,
    ushort_t* __restrict__ xbfT, ushort_t* __restrict__ Wqk,
    ushort_t* __restrict__ Wvb, ushort_t* __restrict__ Wob)
{
  __shared__ float T[64 * 66];
  const int t = threadIdx.x;
  if (blockIdx.y == 8) {
    const int id = blockIdx.z * 16 + blockIdx.x;
    #pragma unroll
    for (int p = 0; p < 5; ++p) {
      const int s = p * 256 + t;
      if (s < 1152) {
        const int u = id * 1152 + s;
        const int e = u * 2;
        float f0, f1;
        if (e < 32768)       { f0 = Wq[e];         f1 = Wq[e + 1]; }
        else if (e < 65536)  { f0 = Wk[e - 32768]; f1 = Wk[e - 32767]; }
        else if (e < 327680) { f0 = Wv[e - 65536]; f1 = Wv[e - 65535]; }
        else                 { f0 = Wo[e - 327680]; f1 = Wo[e - 327679]; }
        const unsigned pk = pk2bf(f0, f1);
        if (e < 65536)       *((unsigned*)Wqk + u) = pk;
        else if (e < 327680) *((unsigned*)Wvb + (u - 32768)) = pk;
        else                 *((unsigned*)Wob + (u - 163840)) = pk;
      }
    }
    return;
  }
  const int b = blockIdx.z, c0 = blockIdx.y * 64, n0 = blockIdx.x * 64;
  const float* xb = x + ((size_t)b * 512 + c0) * 1024 + n0;
  const int njf = t & 15, ci0 = t >> 4;
  #pragma unroll
  for (int p = 0; p < 4; ++p) {
    const int ci = p * 16 + ci0;
    const f32x4 v = *(const f32x4*)(xb + (size_t)ci * 1024 + njf * 4);
    float* d = &T[ci * 66 + njf * 4];
    *(f32x2*)(d)     = (f32x2){v[0], v[1]};
    *(f32x2*)(d + 2) = (f32x2){v[2], v[3]};
  }
  __syncthreads();
  const int c4 = (t & 15) * 4, nr0 = t >> 4;
  #pragma unroll
  for (int p = 0; p < 4; ++p) {
    const int nr = p * 16 + nr0;
    const float a0 = T[(c4 + 0) * 66 + nr];
    const float a1 = T[(c4 + 1) * 66 + nr];
    const float a2 = T[(c4 + 2) * 66 + nr];
    const float a3 = T[(c4 + 3) * 66 + nr];
    const u32x2 pkv = {pk2bf(a0, a1), pk2bf(a2, a3)};
    *(u32x2*)&xbfT[((size_t)b * 1024 + n0 + nr) * 512 + c0 + c4] = pkv;
  }
}

// ---------------------------------------------------------------------------
// k1 fused (512 threads): 640 blocks = 8 XCD x 80; wid batch-contiguous.
__global__ __launch_bounds__(512) void k1_fused(
    const ushort_t* __restrict__ xbfT, const ushort_t* __restrict__ Wqk,
    const ushort_t* __restrict__ Wvb,
    const float* __restrict__ bq, const float* __restrict__ bk,
    const float* __restrict__ bv,
    ushort_t* __restrict__ qkt, ushort_t* __restrict__ vt2)
{
  __shared__ __align__(16) ushort_t lds[17408];
  const unsigned lin = blockIdx.x;
  const unsigned wid = (lin & 7) * 80 + (lin >> 3);
  const int b = wid / 40, r = wid % 40;
  const int t = threadIdx.x, lane = t & 63, quad = lane >> 4, l15 = lane & 15;
  const int w = t >> 6, wm = w >> 2, wn4 = w & 3;
  f32x4 acc[4][2];
  if (r < 32) {
    const int m0 = (r >> 3) * 128, n0 = (r & 7) * 128;
    gemm512(Wvb, 512, xbfT + (size_t)b * 524288, 512, m0, n0,
            lds, lds + 8192, acc);
    float br[4][4];
    #pragma unroll
    for (int i = 0; i < 4; ++i)
      #pragma unroll
      for (int r2 = 0; r2 < 4; ++r2)
        br[i][r2] = bv[m0 + wm * 64 + i * 16 + quad * 4 + r2];
    store_bf16_512(lds, vt2 + (size_t)b * 524288, 1024, m0, n0, acc,
        [&](int i, int, int r2, float v) { return v + br[i][r2]; });
  } else {
    const int m0 = (r - 32) * 128;
    gemm512(xbfT + (size_t)b * 524288, 512, Wqk, 512, m0, 0,
            lds, lds + 8192, acc);
    float bc[2], qs[2];
    #pragma unroll
    for (int j = 0; j < 2; ++j) {
      const int col = wn4 * 32 + j * 16 + l15;
      bc[j] = (col < 64) ? bq[col] : bk[col - 64];
      qs[j] = (col < 64) ? QSCALE : 1.0f;
    }
    store_bf16_512(lds, qkt + (size_t)b * 131072, 128, m0, 0, acc,
        [&](int, int j, int, float v) { return (v + bc[j]) * qs[j]; });
  }
}

// ---------------------------------------------------------------------------
// flash (512 threads): per block (b, 64 q-rows m0, 256 c-cols c0);
// 16 chunks x 64 keys. 8 waves in 2x4 grid: S wave-tile q32xk16 (4 MFMA),
// PV wave-tile q32xc64 (16 MFMA). Single-buffer drain structure (r14).
// LDS: Ks[64][64] | Vs[256][64] | Ps[64][72] = 50176 B. 512 blocks ->
// 2 blocks/CU = 16 waves/CU. + T5 setprio around MFMA clusters.
__global__ __launch_bounds__(512) void flash_attn(
    const ushort_t* __restrict__ qkt, const ushort_t* __restrict__ vt2,
    ushort_t* __restrict__ o1)
{
  __shared__ __align__(16) ushort_t buf[25088];
  __shared__ float lsum[64][4];
  ushort_t* Ks = buf;            // 4096 ush
  ushort_t* Vs = buf + 4096;     // 16384 ush
  ushort_t* Ps = buf + 20480;    // 4608 ush (stride 72); Q-stage uses 4096

  const int t = threadIdx.x;
  const int lane = t & 63, quad = lane >> 4, l15 = lane & 15;
  const int w = t >> 6, wm = w >> 2, wn4 = w & 3;
  const int rr = (lane >> 3) & 7, gg = (lane & 7) ^ rr;

  // bijective XCD swizzle over 512 blocks: XCD k owns batches {2k,2k+1}
  const unsigned lin = blockIdx.x;
  const unsigned wid = (lin & 7) * 64 + (lin >> 3);
  const int b  = wid >> 5;
  const int m0 = ((wid >> 1) & 15) * 64;
  const int c0 = (wid & 1) * 256;

  const ushort_t* qb = qkt + (size_t)b * 131072;   // [n][128]: q 0..63, k 64..127
  const ushort_t* vb = vt2 + (size_t)b * 524288;   // [c][1024]

  // stage Q (64x64) into Ps region: 1 load/thread, wave rows w*8..w*8+7
  gload16(qb + (size_t)(m0 + w * 8 + rr) * 128 + gg * 8, Ps + (w * 8) * 64);
  __syncthreads();
  bf16x8 af_q[2][2];
  #pragma unroll
  for (int kk = 0; kk < 2; ++kk) {
    const int sg = ((kk * 4 + quad) ^ (l15 & 7)) * 8;
    #pragma unroll
    for (int i = 0; i < 2; ++i)
      af_q[i][kk] = *(const bf16x8*)(Ps + (wm * 32 + i * 16 + l15) * 64 + sg);
  }

  f32x4 accO[2][4];
  #pragma unroll
  for (int i = 0; i < 2; ++i)
    #pragma unroll
    for (int j = 0; j < 4; ++j) accO[i][j] = (f32x4){0.f, 0.f, 0.f, 0.f};
  float rsum[2][4] = {{0.f, 0.f, 0.f, 0.f}, {0.f, 0.f, 0.f, 0.f}};

  ushort_t* ps_w = Ps + (wm * 32 + quad * 4) * 72 + wn4 * 16 + l15;
  const int sg0 = (quad ^ (l15 & 7)) * 8;
  const int sg1 = ((4 + quad) ^ (l15 & 7)) * 8;

  #pragma unroll 1
  for (int mc = 0; mc < 1024; mc += 64) {
    __syncthreads();  // A: prev chunk's LDS reads (and Q-frag reads) done
    gload16(qb + (size_t)(mc + w * 8 + rr) * 128 + 64 + gg * 8,
            Ks + (w * 8) * 64);
    #pragma unroll
    for (int i = 0; i < 4; ++i)
      gload16(vb + (size_t)(c0 + w * 32 + i * 8 + rr) * 1024 + mc + gg * 8,
              Vs + (w * 32 + i * 8) * 64);
    __syncthreads();  // B: staged

    // S-phase: rows wm*32+{0,16}, keys wn4*16, K=64 (Q pre-scaled)
    f32x4 accS[2];
    accS[0] = (f32x4){0.f, 0.f, 0.f, 0.f};
    accS[1] = (f32x4){0.f, 0.f, 0.f, 0.f};
    __builtin_amdgcn_s_setprio(1);
    #pragma unroll
    for (int kk = 0; kk < 2; ++kk) {
      const int sg = kk ? sg1 : sg0;
      const bf16x8 bk_ = *(const bf16x8*)(Ks + (wn4 * 16 + l15) * 64 + sg);
      #pragma unroll
      for (int i = 0; i < 2; ++i)
        accS[i] = __builtin_amdgcn_mfma_f32_16x16x32_bf16(
            af_q[i][kk], bk_, accS[i], 0, 0, 0);
    }
    __builtin_amdgcn_s_setprio(0);
    // exp2 -> rsum partials -> Ps (trunc bf16); 8 values/thread
    #pragma unroll
    for (int i = 0; i < 2; ++i)
      #pragma unroll
      for (int r2 = 0; r2 < 4; ++r2) {
        const float e = __builtin_amdgcn_exp2f(accS[i][r2]);
        rsum[i][r2] += e;
        ps_w[(i * 16 + r2) * 72] = f2bf_t(e);
      }
    __syncthreads();  // C: Ps visible

    // PV-phase: O[64][256] += Ps[64][64] . Vs[256][64]^T
    __builtin_amdgcn_s_setprio(1);
    #pragma unroll
    for (int kk = 0; kk < 2; ++kk) {
      const int gq = kk * 4 + quad;
      const int sgv = kk ? sg1 : sg0;
      bf16x8 ap[2], bv_[4];
      #pragma unroll
      for (int i = 0; i < 2; ++i)
        ap[i] = *(const bf16x8*)(Ps + (wm * 32 + i * 16 + l15) * 72 + gq * 8);
      #pragma unroll
      for (int j = 0; j < 4; ++j)
        bv_[j] = *(const bf16x8*)(Vs + (wn4 * 64 + j * 16 + l15) * 64 + sgv);
      #pragma unroll
      for (int i = 0; i < 2; ++i)
        #pragma unroll
        for (int j = 0; j < 4; ++j)
          accO[i][j] = __builtin_amdgcn_mfma_f32_16x16x32_bf16(
              ap[i], bv_[j], accO[i][j], 0, 0, 0);
    }
    __builtin_amdgcn_s_setprio(0);
  }

  // row sums: reduce over 16 key-lanes, store per-wn4 partial
  #pragma unroll
  for (int i = 0; i < 2; ++i)
    #pragma unroll
    for (int r2 = 0; r2 < 4; ++r2) {
      float s = rsum[i][r2];
      #pragma unroll
      for (int d = 1; d < 16; d <<= 1) s += __shfl_xor(s, d, 16);
      if (l15 == 0) lsum[wm * 32 + i * 16 + quad * 4 + r2][wn4] = s;
    }
  __syncthreads();  // last PV reads done; lsum visible

  ushort_t* fl_b = buf;  // [64][264] = 16896 ush (Ks/Vs dead; Ps untouched)
  #pragma unroll
  for (int i = 0; i < 2; ++i)
    #pragma unroll
    for (int r2 = 0; r2 < 4; ++r2) {
      const int row = wm * 32 + i * 16 + quad * 4 + r2;
      const float inv = 1.0f / (lsum[row][0] + lsum[row][1] +
                                lsum[row][2] + lsum[row][3]);
      #pragma unroll
      for (int j = 0; j < 4; ++j)
        fl_b[row * 264 + wn4 * 64 + j * 16 + l15] = f2bf_t(accO[i][j][r2] * inv);
    }
  __syncthreads();
  #pragma unroll
  for (int pp = 0; pp < 2; ++pp) {
    const int s = pp * 512 + t, m = s >> 4, g = s & 15;
    const uint4 v = *(const uint4*)(fl_b + m * 264 + g * 8);
    *(uint4*)(o1 + ((size_t)b * 1024 + m0 + m) * 512 + c0 + g * 8) = v;
  }
}

// ---------------------------------------------------------------------------
// K4 (512 threads): out[b][c][n] = g*(Wo @ o1^T + bo) + x. Exact fp32 path.
__global__ __launch_bounds__(512) void k4_proj(
    const ushort_t* __restrict__ Wob, const ushort_t* __restrict__ o1,
    const float* __restrict__ bo, const float* __restrict__ gamma,
    const float* __restrict__ x, float* __restrict__ out)
{
  __shared__ __align__(16) ushort_t lds[17408];
  const unsigned lin = blockIdx.x;
  const unsigned wid = (lin & 7) * 64 + (lin >> 3);
  const int b = wid >> 5, rem = wid & 31;
  const int m0 = (rem >> 3) * 128, n0 = (rem & 7) * 128;
  f32x4 acc[4][2];
  gemm512(Wob, 512, o1 + (size_t)b * 524288, 512, m0, n0,
          lds, lds + 8192, acc);
  const int t = threadIdx.x, lane = t & 63, quad = lane >> 4, l15 = lane & 15;
  const int w = t >> 6, wm = w >> 2, wn4 = w & 3;
  const float g = gamma[0];
  float br[4][4];
  #pragma unroll
  for (int i = 0; i < 4; ++i)
    #pragma unroll
    for (int r2 = 0; r2 < 4; ++r2)
      br[i][r2] = bo[m0 + wm * 64 + i * 16 + quad * 4 + r2];
  float* fl = (float*)lds;  // 64 rows x 132 f stride (33792 B)
  #pragma unroll
  for (int h = 0; h < 2; ++h) {
    if (wm == h) {
      #pragma unroll
      for (int i = 0; i < 4; ++i)
        #pragma unroll
        for (int j = 0; j < 2; ++j)
          #pragma unroll
          for (int r2 = 0; r2 < 4; ++r2)
            fl[(i * 16 + quad * 4 + r2) * 132 + wn4 * 32 + j * 16 + l15] =
                g * (acc[i][j][r2] + br[i][r2]);
    }
    __syncthreads();
    #pragma unroll
    for (int i2 = 0; i2 < 4; ++i2) {
      const int s = i2 * 512 + t, m = s >> 5, c4 = s & 31;
      f32x4 v = *(const f32x4*)(fl + m * 132 + c4 * 4);
      const size_t gi = ((size_t)b * 512 + m0 + h * 64 + m) * 1024 + n0 + c4 * 4;
      const f32x4 xr = *(const f32x4*)(x + gi);
      v += xr;
      *(f32x4*)(out + gi) = v;
    }
    __syncthreads();
  }
}

// ---------------------------------------------------------------------------
extern "C" void kernel_launch(void* const* d_in, const int* in_sizes, int n_in,
                              void* d_out, int out_size, void* d_ws, size_t ws_size,
                              hipStream_t stream) {
  const float* x     = (const float*)d_in[0];
  const float* Wq    = (const float*)d_in[1];
  const float* bq    = (const float*)d_in[2];
  const float* Wk    = (const float*)d_in[3];
  const float* bk    = (const float*)d_in[4];
  const float* Wv    = (const float*)d_in[5];
  const float* bv    = (const float*)d_in[6];
  const float* Wo    = (const float*)d_in[7];
  const float* bo    = (const float*)d_in[8];
  const float* gamma = (const float*)d_in[9];
  float* out = (float*)d_out;

  char* wsp = (char*)d_ws;
  ushort_t* xbfT   = (ushort_t*)wsp;  wsp += (size_t)16 * 1024 * 512 * 2;  // 16 MB
  ushort_t* Wqk_bf = (ushort_t*)wsp;  wsp += (size_t)128 * 512 * 2;
  ushort_t* Wv_bf  = (ushort_t*)wsp;  wsp += (size_t)512 * 512 * 2;
  ushort_t* Wo_bf  = (ushort_t*)wsp;  wsp += (size_t)512 * 512 * 2;
  ushort_t* qkt    = (ushort_t*)wsp;  wsp += (size_t)16 * 1024 * 128 * 2;  // 4 MB
  ushort_t* vt2    = (ushort_t*)wsp;  wsp += (size_t)16 * 512 * 1024 * 2;  // 16 MB
  ushort_t* o1     = xbfT;  // xbfT dead after k1; reuse for o1

  prep_x    <<<dim3(16, 9, 16), 256, 0, stream>>>(x, Wq, Wk, Wv, Wo,
                                                  xbfT, Wqk_bf, Wv_bf, Wo_bf);
  k1_fused  <<<640, 512, 0, stream>>>(xbfT, Wqk_bf, Wv_bf, bq, bk, bv, qkt, vt2);
  flash_attn<<<512, 512, 0, stream>>>(qkt, vt2, o1);
  k4_proj   <<<512, 512, 0, stream>>>(Wo_bf, o1, bo, gamma, x, out);
}